// Round 6
// baseline (911.162 us; speedup 1.0000x reference)
//
#include <hip/hip_runtime.h>
#include <math.h>

#define H 300
#define BB 64
#define TT 512
#define VV 50257
#define KC 30

// ---------- transpose 300x300: out[r][c] = in[c][r] (U only) ----------
__global__ void transpose_k(const float* __restrict__ in, float* __restrict__ out) {
    int idx = blockIdx.x * blockDim.x + threadIdx.x;
    if (idx < H * H) {
        int r = idx / H, c = idx - r * H;
        out[idx] = in[c * H + r];
    }
}

// ---------- ux[t][b][g] = sum_h emb[tok[b][t]][h] * U[g][h] ----------
// One block per t; 256 threads; micro-tile 4 b-rows x 20 g-cols per thread.
// r5 bug: thread columns at g0=tg*20 -> lanes at 20-dword LDS stride -> ~8-way
// bank conflicts on every ds_read_b128 (ux was ~200us, LDS-conflict-bound).
// Fix: thread owns column quads {tg+16j}, j=0..4 -> consecutive lanes read
// consecutive float4s (canonical conflict-free pattern).
__global__ __launch_bounds__(256) void ux_k(const int* __restrict__ tokens,
                                            const float* __restrict__ emb,
                                            const float* __restrict__ Ut,   // Ut[h][g] = U[g][h]
                                            float* __restrict__ ux) {
    __shared__ __align__(16) float x_s[KC][BB];
    __shared__ __align__(16) float ut_s[KC][304];
    __shared__ int tok_s[BB];

    const int t = blockIdx.x;
    const int tid = threadIdx.x;
    if (tid < BB) tok_s[tid] = tokens[tid * TT + t];

    const int tb = tid >> 4;          // 0..15 -> b0 = 4*tb
    const int tg = tid & 15;          // column quads tg, tg+16, tg+32, tg+48, tg+64
    const int b0 = tb * 4;

    float acc[4][20];                 // [bi][4*j+jj] -> column 4*(tg+16j)+jj
#pragma unroll
    for (int i = 0; i < 4; ++i)
#pragma unroll
        for (int j = 0; j < 20; ++j) acc[i][j] = 0.f;

    __syncthreads();

    for (int h0 = 0; h0 < H; h0 += KC) {
        for (int i = tid; i < BB * 32; i += 256) {
            int b = i >> 5, k = i & 31;
            if (k < KC) x_s[k][b] = emb[tok_s[b] * H + h0 + k];
        }
        for (int i = tid; i < KC * H; i += 256) {
            int k = i / H, g = i - k * H;
            ut_s[k][g] = Ut[(h0 + k) * H + g];
        }
        __syncthreads();
#pragma unroll 2
        for (int k = 0; k < KC; ++k) {
            float4 xa = *reinterpret_cast<const float4*>(&x_s[k][b0]);   // 4-addr broadcast: free
            const float* ur = &ut_s[k][0];
            float4 u[5];
#pragma unroll
            for (int j = 0; j < 5; ++j) {
                const int q = tg + 16 * j;                 // consecutive lanes -> consecutive quads
                u[j] = (q < 75) ? *reinterpret_cast<const float4*>(ur + 4 * q)
                                : make_float4(0.f, 0.f, 0.f, 0.f);
            }
            const float xr[4] = {xa.x, xa.y, xa.z, xa.w};
#pragma unroll
            for (int i = 0; i < 4; ++i)
#pragma unroll
                for (int j = 0; j < 5; ++j) {
                    acc[i][4 * j + 0] += xr[i] * u[j].x;
                    acc[i][4 * j + 1] += xr[i] * u[j].y;
                    acc[i][4 * j + 2] += xr[i] * u[j].z;
                    acc[i][4 * j + 3] += xr[i] * u[j].w;
                }
        }
        __syncthreads();
    }

#pragma unroll
    for (int i = 0; i < 4; ++i) {
        float* dst = ux + (t * BB + b0 + i) * H;
#pragma unroll
        for (int j = 0; j < 5; ++j) {
            const int q = tg + 16 * j;
            if (q < 75)
                *reinterpret_cast<float4*>(dst + 4 * q) =
                    make_float4(acc[i][4 * j + 0], acc[i][4 * j + 1],
                                acc[i][4 * j + 2], acc[i][4 * j + 3]);
        }
    }
}

// ---------- recurrence: one block per batch, 512 threads (8 waves) ----------
// Worker tt<450: c=tt/150, g2=tt%150 owns rows {g2,g2+150} over h-chunk
// [c*100,c*100+100): 50 float4s of W, ALL in registers.
// r5 diagnosis: VGPR=104 with 256 budget => the compiler REMATERIALIZES the
// loop-invariant W loads (L1/L2 re-reads each step) instead of keeping them
// live. Fix: empty asm "+v" on every element makes the values opaque
// (def = asm, not a re-loadable load) -> must stay resident.
// LDS padded >80KB keeps occupancy at 1 block/CU -> 2 waves/SIMD -> 256 VGPR.
#define RNN_REP25(X) X(0) X(1) X(2) X(3) X(4) X(5) X(6) X(7) X(8) X(9) \
    X(10) X(11) X(12) X(13) X(14) X(15) X(16) X(17) X(18) X(19) \
    X(20) X(21) X(22) X(23) X(24)

__global__ __attribute__((amdgpu_flat_work_group_size(512, 512), amdgpu_waves_per_eu(2, 2)))
void rnn_k(const float* __restrict__ W,     // W[g][h] read directly
           const float* __restrict__ ux,    // [T][B][H]
           const float* __restrict__ ihs,
           float* __restrict__ hlast) {
    __shared__ __align__(16) float h_s[304];
    __shared__ float p_s[20608];             // front 608 used; tail pads LDS to 83.6KB
    const int b = blockIdx.x;
    const int tid = threadIdx.x;
    const int tt = (tid < 450) ? tid : 449;  // tail duplicates; writes guarded
    const int c = tt / 150;                  // h-chunk 0..2
    const int g2 = tt - c * 150;             // row pair index 0..149

    const float4* wrA4 = reinterpret_cast<const float4*>(W + (size_t)g2 * H + c * 100);
    const float4* wrB4 = reinterpret_cast<const float4*>(W + (size_t)(g2 + 150) * H + c * 100);

#define RNN_DECL(q) float4 wa##q = wrA4[q]; float4 wb##q = wrB4[q];
    RNN_REP25(RNN_DECL)
#undef RNN_DECL
    // Pin: defeat rematerialization of the W loads.
#define RNN_PIN(q) asm("" : "+v"(wa##q.x), "+v"(wa##q.y), "+v"(wa##q.z), "+v"(wa##q.w), \
                           "+v"(wb##q.x), "+v"(wb##q.y), "+v"(wb##q.z), "+v"(wb##q.w));
    RNN_REP25(RNN_PIN)
#undef RNN_PIN

    if (tid < H) h_s[tid] = ihs[b * H + tid];

    const float* uxb = ux + b * H;
    float u0 = 0.f, u1 = 0.f;
    if (tid < 150) {                          // prefetch t=0
        u0 = uxb[g2];
        u1 = uxb[150 + g2];
    }
    __syncthreads();

    const float4* hs4 = reinterpret_cast<const float4*>(h_s);
    const int hoff = c * 25;

#pragma unroll 1
    for (int t = 0; t < TT; ++t) {
        float n0 = 0.f, n1 = 0.f;
        if (tid < 150 && t + 1 < TT) {        // prefetch t+1 (hides global latency)
            const float* nx = uxb + (t + 1) * (BB * H);
            n0 = nx[g2];
            n1 = nx[150 + g2];
        }
        float accA0 = 0.f, accA1 = 0.f, accA2 = 0.f, accA3 = 0.f;
        float accB0 = 0.f, accB1 = 0.f, accB2 = 0.f, accB3 = 0.f;
#define RNN_Q(q) { float4 h4 = hs4[hoff + q]; \
        accA0 += wa##q.x * h4.x; accA1 += wa##q.y * h4.y; \
        accA2 += wa##q.z * h4.z; accA3 += wa##q.w * h4.w; \
        accB0 += wb##q.x * h4.x; accB1 += wb##q.y * h4.y; \
        accB2 += wb##q.z * h4.z; accB3 += wb##q.w * h4.w; }
        RNN_REP25(RNN_Q)
#undef RNN_Q
        float accA = (accA0 + accA1) + (accA2 + accA3);
        float accB = (accB0 + accB1) + (accB2 + accB3);
        if (tid < 450 && c == 1) { p_s[g2] = accA; p_s[150 + g2] = accB; }
        if (tid < 450 && c == 2) { p_s[304 + g2] = accA; p_s[454 + g2] = accB; }
        __syncthreads();
        if (tid < 150) {
            float z0 = accA + p_s[g2] + p_s[304 + g2] + u0;
            float z1 = accB + p_s[150 + g2] + p_s[454 + g2] + u1;
            // tanh(z) = 1 - 2/(exp(2z)+1); limits give +/-1 exactly
            float e0 = __expf(2.f * z0);
            float e1 = __expf(2.f * z1);
            h_s[g2]       = 1.f - 2.f * __builtin_amdgcn_rcpf(e0 + 1.f);
            h_s[150 + g2] = 1.f - 2.f * __builtin_amdgcn_rcpf(e1 + 1.f);
        }
        u0 = n0; u1 = n1;
        __syncthreads();
    }
    if (tid < H) hlast[b * H + tid] = h_s[tid];
}

// ---------- logits: tiled GEMM  C[64,50257] = h[64,300] . Wout^T ----------
// Block tile [64 b x 128 v], 256 threads, micro-tile 8b x 4v per thread.
__global__ __launch_bounds__(256) void logits_k(const float* __restrict__ hlast,
                                                const float* __restrict__ Wout,
                                                const float* __restrict__ bout,
                                                float* __restrict__ out) {
    __shared__ __align__(16) float Ws[32 * 132];   // Ws[h'][v'], stride 132
    __shared__ __align__(16) float hs[32 * 76];    // hs[h'][b],  stride 76
    const int tid = threadIdx.x;
    const int tv = tid & 31;          // v' = tv*4
    const int tb = tid >> 5;          // b0 = tb*8
    const int v0 = blockIdx.x * 128;

    float acc[8][4];
#pragma unroll
    for (int i = 0; i < 8; ++i)
#pragma unroll
        for (int j = 0; j < 4; ++j) acc[i][j] = 0.f;

    for (int hb = 0; hb < H; hb += 32) {
        __syncthreads();
        {   // stage Wout tile transposed
            const int vp = tid >> 1;
            const int hloc = (tid & 1) * 16;
            int vv = v0 + vp; if (vv > VV - 1) vv = VV - 1;
            const float* wrow = Wout + (size_t)vv * H + hb + hloc;
#pragma unroll
            for (int i = 0; i < 4; ++i) {
                const int hg = hb + hloc + i * 4;
                float4 val;
                if (hg + 3 < H) {
                    val = *reinterpret_cast<const float4*>(wrow + i * 4);
                } else {
                    val.x = (hg + 0 < H) ? wrow[i * 4 + 0] : 0.f;
                    val.y = (hg + 1 < H) ? wrow[i * 4 + 1] : 0.f;
                    val.z = (hg + 2 < H) ? wrow[i * 4 + 2] : 0.f;
                    val.w = (hg + 3 < H) ? wrow[i * 4 + 3] : 0.f;
                }
                Ws[(hloc + i * 4 + 0) * 132 + vp] = val.x;
                Ws[(hloc + i * 4 + 1) * 132 + vp] = val.y;
                Ws[(hloc + i * 4 + 2) * 132 + vp] = val.z;
                Ws[(hloc + i * 4 + 3) * 132 + vp] = val.w;
            }
        }
        {   // stage h tile transposed
            const int bb = tid >> 2;
            const int hl = (tid & 3) * 8;
            const float* hrow = hlast + bb * H + hb + hl;
#pragma unroll
            for (int i = 0; i < 2; ++i) {
                const int hg = hb + hl + i * 4;
                float4 val;
                if (hg + 3 < H) {
                    val = *reinterpret_cast<const float4*>(hrow + i * 4);
                } else {
                    val.x = (hg + 0 < H) ? hrow[i * 4 + 0] : 0.f;
                    val.y = (hg + 1 < H) ? hrow[i * 4 + 1] : 0.f;
                    val.z = (hg + 2 < H) ? hrow[i * 4 + 2] : 0.f;
                    val.w = (hg + 3 < H) ? hrow[i * 4 + 3] : 0.f;
                }
                hs[(hl + i * 4 + 0) * 76 + bb] = val.x;
                hs[(hl + i * 4 + 1) * 76 + bb] = val.y;
                hs[(hl + i * 4 + 2) * 76 + bb] = val.z;
                hs[(hl + i * 4 + 3) * 76 + bb] = val.w;
            }
        }
        __syncthreads();
        const float4* Ws4 = reinterpret_cast<const float4*>(Ws);  // stride 33
        const float4* hs4 = reinterpret_cast<const float4*>(hs);  // stride 19
#pragma unroll
        for (int h2 = 0; h2 < 32; ++h2) {
            float4 w4  = Ws4[h2 * 33 + tv];
            float4 h4a = hs4[h2 * 19 + tb * 2];
            float4 h4b = hs4[h2 * 19 + tb * 2 + 1];
            const float hv[8] = {h4a.x, h4a.y, h4a.z, h4a.w,
                                 h4b.x, h4b.y, h4b.z, h4b.w};
#pragma unroll
            for (int bi = 0; bi < 8; ++bi) {
                acc[bi][0] += hv[bi] * w4.x;
                acc[bi][1] += hv[bi] * w4.y;
                acc[bi][2] += hv[bi] * w4.z;
                acc[bi][3] += hv[bi] * w4.w;
            }
        }
    }

    const int vg = v0 + tv * 4;
    float4 bq;
    if (vg + 3 < VV) bq = *reinterpret_cast<const float4*>(bout + vg);
    else {
        bq.x = (vg + 0 < VV) ? bout[vg + 0] : 0.f;
        bq.y = (vg + 1 < VV) ? bout[vg + 1] : 0.f;
        bq.z = (vg + 2 < VV) ? bout[vg + 2] : 0.f;
        bq.w = (vg + 3 < VV) ? bout[vg + 3] : 0.f;
    }
#pragma unroll
    for (int bi = 0; bi < 8; ++bi) {
        const int bb = tb * 8 + bi;
        float* op = out + (size_t)bb * VV + vg;
        if (vg + 0 < VV) op[0] = acc[bi][0] + bq.x;
        if (vg + 1 < VV) op[1] = acc[bi][1] + bq.y;
        if (vg + 2 < VV) op[2] = acc[bi][2] + bq.z;
        if (vg + 3 < VV) op[3] = acc[bi][3] + bq.w;
    }
}

extern "C" void kernel_launch(void* const* d_in, const int* in_sizes, int n_in,
                              void* d_out, int out_size, void* d_ws, size_t ws_size,
                              hipStream_t stream) {
    const float* ihs    = (const float*)d_in[0];
    const int*   tokens = (const int*)  d_in[1];
    const float* emb    = (const float*)d_in[2];
    const float* W      = (const float*)d_in[3];
    const float* U      = (const float*)d_in[4];
    const float* Wout   = (const float*)d_in[5];
    const float* bout   = (const float*)d_in[6];
    float* out = (float*)d_out;

    char* ws = (char*)d_ws;
    float* Ut    = (float*)(ws + 0);          // 360,000 B
    float* hlast = (float*)(ws + 400000);     // 76,800 B
    float* ux    = (float*)(ws + 1048576);    // 39,321,600 B  [T][B][H]

    const int tp_blocks = (H * H + 255) / 256;
    transpose_k<<<tp_blocks, 256, 0, stream>>>(U, Ut);
    ux_k<<<TT, 256, 0, stream>>>(tokens, emb, Ut, ux);
    rnn_k<<<BB, 512, 0, stream>>>(W, ux, ihs, hlast);
    logits_k<<<(VV + 127) / 128, 256, 0, stream>>>(hlast, Wout, bout, out);
}